// Round 1
// baseline (525.878 us; speedup 1.0000x reference)
//
#include <hip/hip_runtime.h>
#include <cstddef>

#define HW   16384
#define CIN  256

// ---------------- K1: fused h -> flow ----------------
// One block = 32 pixels. Phase 1: h[256][32] in regs (8x4 per thread).
// Phase 2: flow[64][32] from h in LDS.
__global__ __launch_bounds__(256) void k_flow(
    const float* __restrict__ u,  const float* __restrict__ w1,
    const float* __restrict__ b1, const float* __restrict__ w2,
    const float* __restrict__ b2, float* __restrict__ flow)
{
    __shared__ float As[32 * 264];   // W chunk, transposed [k][m], stride 264
    __shared__ float Bs[32 * 32];    // u chunk [k][n]
    __shared__ float hs[256 * 32];   // h [m][n]

    const int t  = threadIdx.x;
    const int pt = blockIdx.x * 32;      // global pixel base (0..65535)
    const int b  = pt >> 14;
    const int p0 = pt & 16383;
    const float* ub = u + (size_t)b * (CIN * HW) + p0;

    const int tm = t >> 3;   // 0..31 -> m = tm*8 + i
    const int tn = t & 7;    // 0..7  -> n = tn*4 + j

    float acc[8][4];
    #pragma unroll
    for (int i = 0; i < 8; ++i)
        #pragma unroll
        for (int j = 0; j < 4; ++j) acc[i][j] = 0.f;

    for (int kc = 0; kc < 256; kc += 32) {
        __syncthreads();
        // stage w1 chunk (256 x 32) transposed into As[k*264 + m]
        #pragma unroll
        for (int j = 0; j < 8; ++j) {
            int m  = j * 32 + (t >> 3);
            int k4 = (t & 7) * 4;
            float4 w4 = *reinterpret_cast<const float4*>(&w1[m * 256 + kc + k4]);
            As[(k4 + 0) * 264 + m] = w4.x;
            As[(k4 + 1) * 264 + m] = w4.y;
            As[(k4 + 2) * 264 + m] = w4.z;
            As[(k4 + 3) * 264 + m] = w4.w;
        }
        // stage u chunk (32 x 32): one float4 per thread
        {
            int k  = t >> 3;          // 0..31
            int n4 = (t & 7) * 4;     // 0..28
            *reinterpret_cast<float4*>(&Bs[k * 32 + n4]) =
                *reinterpret_cast<const float4*>(&ub[(size_t)(kc + k) * HW + n4]);
        }
        __syncthreads();
        #pragma unroll 4
        for (int k = 0; k < 32; ++k) {
            float4 b4 = *reinterpret_cast<const float4*>(&Bs[k * 32 + tn * 4]);
            float4 a0 = *reinterpret_cast<const float4*>(&As[k * 264 + tm * 8]);
            float4 a1 = *reinterpret_cast<const float4*>(&As[k * 264 + tm * 8 + 4]);
            float av[8] = {a0.x, a0.y, a0.z, a0.w, a1.x, a1.y, a1.z, a1.w};
            float bv4[4] = {b4.x, b4.y, b4.z, b4.w};
            #pragma unroll
            for (int i = 0; i < 8; ++i)
                #pragma unroll
                for (int j = 0; j < 4; ++j)
                    acc[i][j] = fmaf(av[i], bv4[j], acc[i][j]);
        }
    }

    // h -> LDS with bias + relu
    #pragma unroll
    for (int i = 0; i < 8; ++i) {
        float bias = b1[tm * 8 + i];
        float4 hv;
        hv.x = fmaxf(acc[i][0] + bias, 0.f);
        hv.y = fmaxf(acc[i][1] + bias, 0.f);
        hv.z = fmaxf(acc[i][2] + bias, 0.f);
        hv.w = fmaxf(acc[i][3] + bias, 0.f);
        *reinterpret_cast<float4*>(&hs[(tm * 8 + i) * 32 + tn * 4]) = hv;
    }

    // Phase 2: flow = w2 @ h + b2   (64 x 32)
    const int tm2 = t >> 4;   // 0..15 -> m2 = tm2*4 + i
    const int tn2 = t & 15;   // 0..15 -> n  = tn2*2 + j
    float acc2[4][2];
    #pragma unroll
    for (int i = 0; i < 4; ++i) { acc2[i][0] = 0.f; acc2[i][1] = 0.f; }

    for (int kc = 0; kc < 256; kc += 32) {
        __syncthreads();   // also guards As reuse + hs visibility on first iter
        // stage w2 chunk (64 x 32) transposed into As[k*72 + m], stride 72
        #pragma unroll
        for (int j = 0; j < 2; ++j) {
            int m  = j * 32 + (t >> 3);
            int k4 = (t & 7) * 4;
            float4 w4 = *reinterpret_cast<const float4*>(&w2[m * 256 + kc + k4]);
            As[(k4 + 0) * 72 + m] = w4.x;
            As[(k4 + 1) * 72 + m] = w4.y;
            As[(k4 + 2) * 72 + m] = w4.z;
            As[(k4 + 3) * 72 + m] = w4.w;
        }
        __syncthreads();
        #pragma unroll 4
        for (int k = 0; k < 32; ++k) {
            float4 a  = *reinterpret_cast<const float4*>(&As[k * 72 + tm2 * 4]);
            float2 h2 = *reinterpret_cast<const float2*>(&hs[(kc + k) * 32 + tn2 * 2]);
            acc2[0][0] = fmaf(a.x, h2.x, acc2[0][0]);
            acc2[0][1] = fmaf(a.x, h2.y, acc2[0][1]);
            acc2[1][0] = fmaf(a.y, h2.x, acc2[1][0]);
            acc2[1][1] = fmaf(a.y, h2.y, acc2[1][1]);
            acc2[2][0] = fmaf(a.z, h2.x, acc2[2][0]);
            acc2[2][1] = fmaf(a.z, h2.y, acc2[2][1]);
            acc2[3][0] = fmaf(a.w, h2.x, acc2[3][0]);
            acc2[3][1] = fmaf(a.w, h2.y, acc2[3][1]);
        }
    }
    #pragma unroll
    for (int i = 0; i < 4; ++i) {
        int m2 = tm2 * 4 + i;
        float bias = b2[m2];
        float* fp = flow + ((size_t)b * 64 + m2) * HW + p0 + tn2 * 2;
        fp[0] = acc2[i][0] + bias;
        fp[1] = acc2[i][1] + bias;
    }
}

// ---------------- K2: value = wv @ u + bv ----------------
// 64x64 tile, 4x4 micro-tile, Kc=32
__global__ __launch_bounds__(256) void k_value(
    const float* __restrict__ u,  const float* __restrict__ wv,
    const float* __restrict__ bv, float* __restrict__ value)
{
    __shared__ float As[32 * 72];    // [k][m], stride 72
    __shared__ float Bs[32 * 64];    // [k][n]

    const int t  = threadIdx.x;
    const int pt = blockIdx.x * 64;
    const int mt = blockIdx.y * 64;
    const int b  = pt >> 14;
    const int p0 = pt & 16383;
    const float* ub = u + (size_t)b * (CIN * HW) + p0;

    const int tm = t >> 4;   // 0..15
    const int tn = t & 15;   // 0..15

    float acc[4][4];
    #pragma unroll
    for (int i = 0; i < 4; ++i)
        #pragma unroll
        for (int j = 0; j < 4; ++j) acc[i][j] = 0.f;

    for (int kc = 0; kc < 256; kc += 32) {
        __syncthreads();
        // A: wv tile (64 x 32) transposed
        #pragma unroll
        for (int j = 0; j < 2; ++j) {
            int m  = j * 32 + (t >> 3);
            int k4 = (t & 7) * 4;
            float4 w4 = *reinterpret_cast<const float4*>(&wv[(mt + m) * 256 + kc + k4]);
            As[(k4 + 0) * 72 + m] = w4.x;
            As[(k4 + 1) * 72 + m] = w4.y;
            As[(k4 + 2) * 72 + m] = w4.z;
            As[(k4 + 3) * 72 + m] = w4.w;
        }
        // B: u tile (32 x 64)
        #pragma unroll
        for (int j = 0; j < 2; ++j) {
            int l  = j * 256 + t;
            int k  = l >> 4;          // 0..31
            int n4 = (l & 15) * 4;    // 0..60
            *reinterpret_cast<float4*>(&Bs[k * 64 + n4]) =
                *reinterpret_cast<const float4*>(&ub[(size_t)(kc + k) * HW + n4]);
        }
        __syncthreads();
        #pragma unroll 4
        for (int k = 0; k < 32; ++k) {
            float4 a  = *reinterpret_cast<const float4*>(&As[k * 72 + tm * 4]);
            float4 b4 = *reinterpret_cast<const float4*>(&Bs[k * 64 + tn * 4]);
            float av[4]  = {a.x, a.y, a.z, a.w};
            float bv4[4] = {b4.x, b4.y, b4.z, b4.w};
            #pragma unroll
            for (int i = 0; i < 4; ++i)
                #pragma unroll
                for (int j = 0; j < 4; ++j)
                    acc[i][j] = fmaf(av[i], bv4[j], acc[i][j]);
        }
    }
    #pragma unroll
    for (int i = 0; i < 4; ++i) {
        int m = mt + tm * 4 + i;
        float bias = bv[m];
        float4 v;
        v.x = acc[i][0] + bias;
        v.y = acc[i][1] + bias;
        v.z = acc[i][2] + bias;
        v.w = acc[i][3] + bias;
        *reinterpret_cast<float4*>(&value[((size_t)b * 256 + m) * HW + p0 + tn * 4]) = v;
    }
}

// ---------------- K3: bilinear warp ----------------
// one thread per (b, head, pixel), 8 channels each
__global__ __launch_bounds__(256) void k_warp(
    const float* __restrict__ flow, const float* __restrict__ value,
    float* __restrict__ out)
{
    const int g = blockIdx.x * 256 + threadIdx.x;  // 0 .. 128*16384-1
    const int p = g & 16383;
    const int n = g >> 14;        // b*32 + head
    const int b = n >> 5;
    const int head = n & 31;
    const int y = p >> 7;
    const int x = p & 127;

    float fx = flow[((size_t)b * 64 + 2 * head + 0) * HW + p];
    float fy = flow[((size_t)b * 64 + 2 * head + 1) * HW + p];
    float ix = (float)x + fx * 63.5f;
    float iy = (float)y + fy * 63.5f;

    float x0f = floorf(ix), y0f = floorf(iy);
    float dx = ix - x0f, dy = iy - y0f;
    int x0 = (int)x0f, y0 = (int)y0f;
    int x1 = x0 + 1,   y1 = y0 + 1;

    bool vx0 = (x0 >= 0) & (x0 < 128);
    bool vx1 = (x1 >= 0) & (x1 < 128);
    bool vy0 = (y0 >= 0) & (y0 < 128);
    bool vy1 = (y1 >= 0) & (y1 < 128);

    int x0c = min(max(x0, 0), 127), x1c = min(max(x1, 0), 127);
    int y0c = min(max(y0, 0), 127), y1c = min(max(y1, 0), 127);

    float w00 = (1.f - dx) * (1.f - dy) * ((vx0 & vy0) ? 1.f : 0.f);
    float w10 = dx * (1.f - dy)        * ((vx1 & vy0) ? 1.f : 0.f);
    float w01 = (1.f - dx) * dy        * ((vx0 & vy1) ? 1.f : 0.f);
    float w11 = dx * dy                * ((vx1 & vy1) ? 1.f : 0.f);

    int o00 = y0c * 128 + x0c;
    int o10 = y0c * 128 + x1c;
    int o01 = y1c * 128 + x0c;
    int o11 = y1c * 128 + x1c;

    const float* vb = value + ((size_t)b * 256 + head * 8) * HW;
    float* ob = out + ((size_t)b * 256 + head * 8) * HW + p;
    #pragma unroll
    for (int ci = 0; ci < 8; ++ci) {
        const float* vp = vb + (size_t)ci * HW;
        ob[(size_t)ci * HW] =
            w00 * vp[o00] + w10 * vp[o10] + w01 * vp[o01] + w11 * vp[o11];
    }
}

extern "C" void kernel_launch(void* const* d_in, const int* in_sizes, int n_in,
                              void* d_out, int out_size, void* d_ws, size_t ws_size,
                              hipStream_t stream) {
    const float* u  = (const float*)d_in[0];
    const float* w1 = (const float*)d_in[1];
    const float* b1 = (const float*)d_in[2];
    const float* w2 = (const float*)d_in[3];
    const float* b2 = (const float*)d_in[4];
    const float* wv = (const float*)d_in[5];
    const float* bv = (const float*)d_in[6];
    float* out = (float*)d_out;

    float* value = (float*)d_ws;                      // 4*256*HW floats = 64 MiB
    float* flow  = value + (size_t)4 * 256 * HW;      // 4*64*HW floats = 16 MiB

    k_flow <<<dim3(65536 / 32), dim3(256), 0, stream>>>(u, w1, b1, w2, b2, flow);
    k_value<<<dim3(65536 / 64, 4), dim3(256), 0, stream>>>(u, wv, bv, value);
    k_warp <<<dim3((128 * HW) / 256), dim3(256), 0, stream>>>(flow, value, out);
}

// Round 2
// 263.768 us; speedup vs baseline: 1.9937x; 1.9937x over previous
//
#include <hip/hip_runtime.h>
#include <cstddef>

#define HW 16384

typedef short s8v __attribute__((ext_vector_type(8)));
typedef short s4v __attribute__((ext_vector_type(4)));
typedef float f4v __attribute__((ext_vector_type(4)));

__device__ inline short f2b(float x) {
    union { float f; unsigned u; } v; v.f = x;
    unsigned r = v.u + 0x7fff + ((v.u >> 16) & 1);
    return (short)(r >> 16);
}
__device__ inline float b2f(short h) {
    union { unsigned u; float f; } v;
    v.u = ((unsigned)(unsigned short)h) << 16;
    return v.f;
}
__device__ inline void gload_lds16(const void* gsrc, void* ldst) {
    __builtin_amdgcn_global_load_lds(
        (const __attribute__((address_space(1))) unsigned int*)gsrc,
        (__attribute__((address_space(3))) unsigned int*)ldst, 16, 0, 0);
}

// ---------------- k_prep: weights fp32 -> bf16 hi (+lo for w1) ----------------
// Whi[512][256]: rows 0..255 = w1, 256..511 = wv.  Wlo[256][256]: w1 lo part.
__global__ __launch_bounds__(256) void k_prep(
    const float* __restrict__ w1, const float* __restrict__ wv,
    short* __restrict__ Whi, short* __restrict__ Wlo)
{
    int g = blockIdx.x * 256 + threadIdx.x;   // 0 .. 131071
    float f = (g < 65536) ? w1[g] : wv[g - 65536];
    short hi = f2b(f);
    Whi[g] = hi;
    if (g < 65536) Wlo[g] = f2b(f - b2f(hi));
}

// ---------------- k_gemm1: C[pixel][channel] = u^T @ W^T ----------------
// M = 128 pixels/block, N = 128 channels/block (nb 0,1 = h(w1, split bf16),
// nb 2,3 = value(wv, plain bf16)), K = 256, BK = 32.
// h -> fp32 pixel-major into hbuf (=d_out), value -> bf16 pixel-major into vbuf.
__global__ __launch_bounds__(256) void k_gemm1(
    const float* __restrict__ u,
    const short* __restrict__ Whi, const short* __restrict__ Wlo,
    const float* __restrict__ b1, const float* __restrict__ bv,
    float* __restrict__ hbuf, unsigned short* __restrict__ vbuf)
{
    __shared__ short Ah[128 * 36];   // u hi, [px][k], stride 36 (bank spread)
    __shared__ short Al[128 * 36];   // u lo (h-blocks only)
    __shared__ short Bs[128 * 32];   // W hi, [ch][k], stride 32 (global_load_lds order)
    __shared__ short Bl[128 * 32];   // W lo

    const int t  = threadIdx.x;
    const int l  = t & 63;
    const int w  = t >> 6;
    const int nb = blockIdx.y;
    const bool is_h = (nb < 2);
    const int pt = blockIdx.x * 128;
    const int b  = pt >> 14;
    const int p0 = pt & 16383;
    const int cbase = nb * 128;

    const float* ub = u + (size_t)b * (256 * HW) + p0;

    f4v acc[4][4];
    #pragma unroll
    for (int i = 0; i < 4; ++i)
        #pragma unroll
        for (int j = 0; j < 4; ++j) acc[i][j] = (f4v){0.f, 0.f, 0.f, 0.f};

    const int q  = t & 31;   // pixel quad (4 px each)
    const int kb = t >> 5;   // k block (4 k each)

    const int m0 = (w >> 1) * 64;
    const int n0 = (w & 1) * 64;
    const int lr = l & 15;
    const int koff = (l >> 4) * 8;

    for (int kc = 0; kc < 256; kc += 32) {
        __syncthreads();
        // ---- A: u transpose + split into LDS ----
        {
            const float* up = ub + (size_t)(kc + kb * 4) * HW + q * 4;
            float4 r0 = *reinterpret_cast<const float4*>(up);
            float4 r1 = *reinterpret_cast<const float4*>(up + HW);
            float4 r2 = *reinterpret_cast<const float4*>(up + 2 * HW);
            float4 r3 = *reinterpret_cast<const float4*>(up + 3 * HW);
            auto stageA = [&](int j, float f0, float f1, float f2, float f3) {
                short h0 = f2b(f0), h1 = f2b(f1), h2 = f2b(f2), h3 = f2b(f3);
                s4v hv = {h0, h1, h2, h3};
                *reinterpret_cast<s4v*>(&Ah[(q * 4 + j) * 36 + kb * 4]) = hv;
                if (is_h) {
                    s4v lv = {f2b(f0 - b2f(h0)), f2b(f1 - b2f(h1)),
                              f2b(f2 - b2f(h2)), f2b(f3 - b2f(h3))};
                    *reinterpret_cast<s4v*>(&Al[(q * 4 + j) * 36 + kb * 4]) = lv;
                }
            };
            stageA(0, r0.x, r1.x, r2.x, r3.x);
            stageA(1, r0.y, r1.y, r2.y, r3.y);
            stageA(2, r0.z, r1.z, r2.z, r3.z);
            stageA(3, r0.w, r1.w, r2.w, r3.w);
        }
        // ---- B: weights hi (+lo) via 16B global_load_lds ----
        {
            int row0 = w * 32;
            #pragma unroll
            for (int qq = 0; qq < 2; ++qq) {
                int row = row0 + qq * 16 + (l >> 2);
                int kp  = (l & 3) * 8;
                gload_lds16(Whi + (size_t)(cbase + row) * 256 + kc + kp,
                            &Bs[(row0 + qq * 16) * 32]);
                if (is_h)
                    gload_lds16(Wlo + (size_t)(cbase + row) * 256 + kc + kp,
                                &Bl[(row0 + qq * 16) * 32]);
            }
        }
        __syncthreads();

        // ---- fragments + MFMA ----
        s8v ah[4], alv[4], bh[4], blv[4];
        #pragma unroll
        for (int i = 0; i < 4; ++i) {
            int m = m0 + i * 16 + lr;
            union { s8v v; s4v h[2]; } ua;
            ua.h[0] = *reinterpret_cast<const s4v*>(&Ah[m * 36 + koff]);
            ua.h[1] = *reinterpret_cast<const s4v*>(&Ah[m * 36 + koff + 4]);
            ah[i] = ua.v;
            if (is_h) {
                union { s8v v; s4v h[2]; } ul;
                ul.h[0] = *reinterpret_cast<const s4v*>(&Al[m * 36 + koff]);
                ul.h[1] = *reinterpret_cast<const s4v*>(&Al[m * 36 + koff + 4]);
                alv[i] = ul.v;
            }
        }
        #pragma unroll
        for (int j = 0; j < 4; ++j) {
            int n = n0 + j * 16 + lr;
            bh[j] = *reinterpret_cast<const s8v*>(&Bs[n * 32 + koff]);
            if (is_h) blv[j] = *reinterpret_cast<const s8v*>(&Bl[n * 32 + koff]);
        }
        #pragma unroll
        for (int i = 0; i < 4; ++i)
            #pragma unroll
            for (int j = 0; j < 4; ++j) {
                acc[i][j] = __builtin_amdgcn_mfma_f32_16x16x32_bf16(ah[i], bh[j], acc[i][j], 0, 0, 0);
                if (is_h) {
                    acc[i][j] = __builtin_amdgcn_mfma_f32_16x16x32_bf16(ah[i], blv[j], acc[i][j], 0, 0, 0);
                    acc[i][j] = __builtin_amdgcn_mfma_f32_16x16x32_bf16(alv[i], bh[j], acc[i][j], 0, 0, 0);
                }
            }
    }

    // ---- epilogue: C/D layout col=lane&15, row=(lane>>4)*4+reg ----
    const int quad = l >> 4;
    #pragma unroll
    for (int j = 0; j < 4; ++j) {
        int nloc = n0 + j * 16 + lr;
        int c = cbase + nloc;                  // 0..511 stacked
        float bias = is_h ? b1[c] : bv[c - 256];
        #pragma unroll
        for (int i = 0; i < 4; ++i)
            #pragma unroll
            for (int r = 0; r < 4; ++r) {
                int m = m0 + i * 16 + quad * 4 + r;   // local pixel
                size_t pixrow = (size_t)(b << 14) + p0 + m;
                float v = acc[i][j][r] + bias;
                if (is_h) hbuf[pixrow * 256 + c] = fmaxf(v, 0.f);
                else      vbuf[pixrow * 256 + (c - 256)] = (unsigned short)f2b(v);
            }
    }
}

// ---------------- k_gemm2: flow[dir][pixel] = w2 @ relu(h), split bf16 ----------------
// M = 64 dirs, N-tile = 128 pixels, K = 256 (h channels), BK = 32.
__global__ __launch_bounds__(256) void k_gemm2(
    const float* __restrict__ h, const float* __restrict__ w2,
    const float* __restrict__ b2, float* __restrict__ flow)
{
    __shared__ short A2h[64 * 36], A2l[64 * 36];
    __shared__ short B2h[128 * 36], B2l[128 * 36];

    const int t = threadIdx.x;
    const int l = t & 63;
    const int w = t >> 6;
    const int pt = blockIdx.x * 128;
    const int b  = pt >> 14;
    const int p0 = pt & 16383;

    f4v acc[8];
    #pragma unroll
    for (int j = 0; j < 8; ++j) acc[j] = (f4v){0.f, 0.f, 0.f, 0.f};

    const int lr = l & 15;
    const int koff = (l >> 4) * 8;

    for (int kc = 0; kc < 256; kc += 32) {
        __syncthreads();
        // stage A: w2 (64 x 32) hi/lo
        #pragma unroll
        for (int i = 0; i < 2; ++i) {
            int s = t + 256 * i;           // 0..511
            int row = s >> 3, k4 = (s & 7) * 4;
            float4 v = *reinterpret_cast<const float4*>(&w2[row * 256 + kc + k4]);
            short h0 = f2b(v.x), h1 = f2b(v.y), h2 = f2b(v.z), h3 = f2b(v.w);
            s4v hv = {h0, h1, h2, h3};
            s4v lv = {f2b(v.x - b2f(h0)), f2b(v.y - b2f(h1)),
                      f2b(v.z - b2f(h2)), f2b(v.w - b2f(h3))};
            *reinterpret_cast<s4v*>(&A2h[row * 36 + k4]) = hv;
            *reinterpret_cast<s4v*>(&A2l[row * 36 + k4]) = lv;
        }
        // stage B: h (128 px x 32 ch) hi/lo
        #pragma unroll
        for (int i = 0; i < 4; ++i) {
            int s = t + 256 * i;           // 0..1023
            int px = s >> 3, k4 = (s & 7) * 4;
            float4 v = *reinterpret_cast<const float4*>(
                &h[((size_t)(b << 14) + p0 + px) * 256 + kc + k4]);
            short h0 = f2b(v.x), h1 = f2b(v.y), h2 = f2b(v.z), h3 = f2b(v.w);
            s4v hv = {h0, h1, h2, h3};
            s4v lv = {f2b(v.x - b2f(h0)), f2b(v.y - b2f(h1)),
                      f2b(v.z - b2f(h2)), f2b(v.w - b2f(h3))};
            *reinterpret_cast<s4v*>(&B2h[px * 36 + k4]) = hv;
            *reinterpret_cast<s4v*>(&B2l[px * 36 + k4]) = lv;
        }
        __syncthreads();

        union { s8v v; s4v h[2]; } ua, ul;
        int am = w * 16 + lr;
        ua.h[0] = *reinterpret_cast<const s4v*>(&A2h[am * 36 + koff]);
        ua.h[1] = *reinterpret_cast<const s4v*>(&A2h[am * 36 + koff + 4]);
        ul.h[0] = *reinterpret_cast<const s4v*>(&A2l[am * 36 + koff]);
        ul.h[1] = *reinterpret_cast<const s4v*>(&A2l[am * 36 + koff + 4]);
        s8v a_h = ua.v, a_l = ul.v;

        #pragma unroll
        for (int j = 0; j < 8; ++j) {
            int pxr = j * 16 + lr;
            union { s8v v; s4v h[2]; } ub_, ubl;
            ub_.h[0] = *reinterpret_cast<const s4v*>(&B2h[pxr * 36 + koff]);
            ub_.h[1] = *reinterpret_cast<const s4v*>(&B2h[pxr * 36 + koff + 4]);
            ubl.h[0] = *reinterpret_cast<const s4v*>(&B2l[pxr * 36 + koff]);
            ubl.h[1] = *reinterpret_cast<const s4v*>(&B2l[pxr * 36 + koff + 4]);
            acc[j] = __builtin_amdgcn_mfma_f32_16x16x32_bf16(a_h, ub_.v, acc[j], 0, 0, 0);
            acc[j] = __builtin_amdgcn_mfma_f32_16x16x32_bf16(a_h, ubl.v, acc[j], 0, 0, 0);
            acc[j] = __builtin_amdgcn_mfma_f32_16x16x32_bf16(a_l, ub_.v, acc[j], 0, 0, 0);
        }
    }

    const int quad = l >> 4;
    #pragma unroll
    for (int r = 0; r < 4; ++r) {
        int m = w * 16 + quad * 4 + r;
        float bias = b2[m];
        #pragma unroll
        for (int j = 0; j < 8; ++j)
            flow[((size_t)b * 64 + m) * HW + p0 + j * 16 + lr] = acc[j][r] + bias;
    }
}

// ---------------- k_warp: bilinear gather from bf16 pixel-major value ----------------
__global__ __launch_bounds__(256) void k_warp(
    const float* __restrict__ flow, const unsigned short* __restrict__ vbuf,
    float* __restrict__ out)
{
    const int g = blockIdx.x * 256 + threadIdx.x;
    const int p = g & 16383;
    const int n = g >> 14;
    const int b = n >> 5;
    const int head = n & 31;
    const int y = p >> 7;
    const int x = p & 127;

    float fx = flow[((size_t)b * 64 + 2 * head + 0) * HW + p];
    float fy = flow[((size_t)b * 64 + 2 * head + 1) * HW + p];
    float ix = (float)x + fx * 63.5f;
    float iy = (float)y + fy * 63.5f;

    float x0f = floorf(ix), y0f = floorf(iy);
    float dx = ix - x0f, dy = iy - y0f;
    int x0 = (int)x0f, y0 = (int)y0f;
    int x1 = x0 + 1,   y1 = y0 + 1;

    bool vx0 = (x0 >= 0) & (x0 < 128);
    bool vx1 = (x1 >= 0) & (x1 < 128);
    bool vy0 = (y0 >= 0) & (y0 < 128);
    bool vy1 = (y1 >= 0) & (y1 < 128);
    int x0c = min(max(x0, 0), 127), x1c = min(max(x1, 0), 127);
    int y0c = min(max(y0, 0), 127), y1c = min(max(y1, 0), 127);

    float w00 = (1.f - dx) * (1.f - dy) * ((vx0 & vy0) ? 1.f : 0.f);
    float w10 = dx * (1.f - dy)        * ((vx1 & vy0) ? 1.f : 0.f);
    float w01 = (1.f - dx) * dy        * ((vx0 & vy1) ? 1.f : 0.f);
    float w11 = dx * dy                * ((vx1 & vy1) ? 1.f : 0.f);

    const unsigned short* vb = vbuf + ((size_t)(b << 14)) * 256 + head * 8;
    s8v v00 = *reinterpret_cast<const s8v*>(vb + (size_t)(y0c * 128 + x0c) * 256);
    s8v v10 = *reinterpret_cast<const s8v*>(vb + (size_t)(y0c * 128 + x1c) * 256);
    s8v v01 = *reinterpret_cast<const s8v*>(vb + (size_t)(y1c * 128 + x0c) * 256);
    s8v v11 = *reinterpret_cast<const s8v*>(vb + (size_t)(y1c * 128 + x1c) * 256);

    float* ob = out + ((size_t)b * 256 + head * 8) * HW + p;
    #pragma unroll
    for (int ci = 0; ci < 8; ++ci) {
        float v = w00 * b2f(v00[ci]) + w10 * b2f(v10[ci])
                + w01 * b2f(v01[ci]) + w11 * b2f(v11[ci]);
        ob[(size_t)ci * HW] = v;
    }
}

extern "C" void kernel_launch(void* const* d_in, const int* in_sizes, int n_in,
                              void* d_out, int out_size, void* d_ws, size_t ws_size,
                              hipStream_t stream) {
    const float* u  = (const float*)d_in[0];
    const float* w1 = (const float*)d_in[1];
    const float* b1 = (const float*)d_in[2];
    const float* w2 = (const float*)d_in[3];
    const float* b2 = (const float*)d_in[4];
    const float* wv = (const float*)d_in[5];
    const float* bv = (const float*)d_in[6];

    unsigned char* ws = (unsigned char*)d_ws;
    unsigned short* vbuf = (unsigned short*)ws;                       // 32 MiB bf16 value
    float* flow = (float*)(ws + (32ull << 20));                       // 16 MiB
    short* Whi  = (short*)(ws + (48ull << 20));                       // 256 KiB
    short* Wlo  = (short*)(ws + (48ull << 20) + (256ull << 10));      // 128 KiB
    float* hbuf = (float*)d_out;                                      // h parked in d_out
    float* out  = (float*)d_out;

    k_prep <<<dim3(512),      dim3(256), 0, stream>>>(w1, wv, Whi, Wlo);
    k_gemm1<<<dim3(512, 4),   dim3(256), 0, stream>>>(u, Whi, Wlo, b1, bv, hbuf, vbuf);
    k_gemm2<<<dim3(512),      dim3(256), 0, stream>>>(hbuf, w2, b2, flow);
    k_warp <<<dim3(8192),     dim3(256), 0, stream>>>(flow, vbuf, out);
}